// Round 6
// baseline (1007.729 us; speedup 1.0000x reference)
//
#include <hip/hip_runtime.h>
#include <hip/hip_bf16.h>
#include <stdint.h>

#define AS1 __attribute__((address_space(1)))
#define AS3 __attribute__((address_space(3)))

typedef __bf16 bf16x8 __attribute__((ext_vector_type(8)));
typedef __bf16 bf16x4 __attribute__((ext_vector_type(4)));
typedef float  f32x4  __attribute__((ext_vector_type(4)));

static constexpr int kL   = 8192;
static constexpr int kD   = 1024;
static constexpr int kdh  = 128;
static constexpr int kM   = 2 * kL;         // 16384 token rows
static constexpr int kNCH = 32;             // KV partial chunks over L
static constexpr int kSCH = kL / kNCH;      // 256 s-rows per chunk

__device__ __forceinline__ void async_cp16(__bf16* lds, const __bf16* g) {
    __builtin_amdgcn_global_load_lds((AS1 uint32_t*)g, (AS3 uint32_t*)lds, 16, 0, 0);
}

__device__ __forceinline__ float elu1f(float x) {
    return x > 0.0f ? x + 1.0f : __expf(x);
}

// ---------------------------------------------------------------------------
// GEMM: C[M,N] = A[M,K] @ B[K,N], B supplied transposed (Bt[N,K] row-major).
// 128x128 tile, BK=32, 256 thr = 4 waves, each wave 4x4 mfma_16x16x32_bf16.
//
// R6 "flatmm" structure: B (weights) goes through LDS (DMA double-buffer,
// R4 swizzle -> 0 bank conflicts); A is loaded DIRECTLY global->VGPR
// fragments, double-buffered in registers one K-iter ahead. The A-fragment
// global pattern is 16 rows x 64B contiguous segments per instruction -
// identical coalescing to the DMA staging, zero extra HBM bytes - but it
// removes half the LDS traffic (R5: 48 KB/blk-iter -> 24 KB), which the R5
// counters identified as the cap (MFMA+VALU=34%, LDS-bound ~380cyc/iter vs
// 155cyc MFMA). K-loop manually unrolled 2x so reg buffers stay static.
// EPI: 0 = plain bf16 store, 1 = relu.
// ---------------------------------------------------------------------------
template <int EPI>
__global__ __launch_bounds__(256) void gemm_bt(const __bf16* __restrict__ A,
                                               const __bf16* __restrict__ Bt,
                                               __bf16* __restrict__ C,
                                               int M, int N, int K) {
    __shared__ __bf16 Bs[2][128 * 32];
    const int tid  = threadIdx.x;
    const int wave = tid >> 6;
    const int lane = tid & 63;
    const int quad = lane >> 4;
    const int l16  = lane & 15;
    const int row0 = blockIdx.x * 128;
    const int col0 = blockIdx.y * 128;
    const int wm   = wave & 1;
    const int wn   = wave >> 1;

    f32x4 acc[4][4] = {};

    // ---- B staging (swizzled, R4): lane l=4r+c stages chunk (c-(r>>1))&3
    const int srow = lane >> 2;
    const int sk8  = ((lane & 3) - (srow >> 1)) & 3;
    const __bf16* Bg0 = Bt + (size_t)(col0 + wave * 32 + srow) * K + sk8 * 8;
    const size_t r16 = (size_t)16 * K;
    const int ldsw = wave * 1024;            // wave's 32-row span base

    // B fragment LDS offset: position p = (quad+(l16>>1))&3
    const int frow = l16 * 32 + ((quad + (l16 >> 1)) & 3) * 8;

    // ---- A direct global fragment base: frag i row = row0+wm*64+i*16+l16
    const __bf16* Agl = A + (size_t)(row0 + wm * 64 + l16) * K + quad * 8;

    const int nk = K >> 5;
    bf16x8 ra[4], rb[4];

    // prologue: DMA B(0) -> buf0, load A(0) -> ra
    async_cp16(&Bs[0][ldsw], Bg0);
    async_cp16(&Bs[0][ldsw + 512], Bg0 + r16);
#pragma unroll
    for (int i = 0; i < 4; ++i) ra[i] = *(const bf16x8*)(Agl + (size_t)i * r16);

    for (int kp = 0; kp < nk; kp += 2) {
        // ---------- even half: compute kp from buf0/ra ----------
        __syncthreads();   // B(kp) resident; all waves done with buf1
        if (kp + 1 < nk) {
            const int ko = (kp + 1) << 5;
            async_cp16(&Bs[1][ldsw], Bg0 + ko);
            async_cp16(&Bs[1][ldsw + 512], Bg0 + r16 + ko);
#pragma unroll
            for (int i = 0; i < 4; ++i)
                rb[i] = *(const bf16x8*)(Agl + (size_t)i * r16 + ko);
        }
        {
            bf16x8 bfr[4];
#pragma unroll
            for (int j = 0; j < 4; ++j)
                bfr[j] = *(const bf16x8*)&Bs[0][(wn * 4 + j) * 512 + frow];
#pragma unroll
            for (int i = 0; i < 4; ++i)
#pragma unroll
                for (int j = 0; j < 4; ++j)
                    acc[i][j] = __builtin_amdgcn_mfma_f32_16x16x32_bf16(ra[i], bfr[j], acc[i][j], 0, 0, 0);
        }
        if (kp + 1 >= nk) break;
        // ---------- odd half: compute kp+1 from buf1/rb ----------
        __syncthreads();   // B(kp+1) resident; all waves done with buf0
        if (kp + 2 < nk) {
            const int ko = (kp + 2) << 5;
            async_cp16(&Bs[0][ldsw], Bg0 + ko);
            async_cp16(&Bs[0][ldsw + 512], Bg0 + r16 + ko);
#pragma unroll
            for (int i = 0; i < 4; ++i)
                ra[i] = *(const bf16x8*)(Agl + (size_t)i * r16 + ko);
        }
        {
            bf16x8 bfr[4];
#pragma unroll
            for (int j = 0; j < 4; ++j)
                bfr[j] = *(const bf16x8*)&Bs[1][(wn * 4 + j) * 512 + frow];
#pragma unroll
            for (int i = 0; i < 4; ++i)
#pragma unroll
                for (int j = 0; j < 4; ++j)
                    acc[i][j] = __builtin_amdgcn_mfma_f32_16x16x32_bf16(rb[i], bfr[j], acc[i][j], 0, 0, 0);
        }
    }

    // D layout (m89-verified): col = l16, row = quad*4 + reg
#pragma unroll
    for (int i = 0; i < 4; ++i) {
        const int row_b = row0 + wm * 64 + i * 16 + quad * 4;
#pragma unroll
        for (int j = 0; j < 4; ++j) {
            const int col = col0 + wn * 64 + j * 16 + l16;
#pragma unroll
            for (int r = 0; r < 4; ++r) {
                float v = acc[i][j][r];
                if (EPI == 1) v = v > 0.0f ? v : 0.0f;
                C[(size_t)(row_b + r) * N + col] = (__bf16)v;
            }
        }
    }
}

// ---------------------------------------------------------------------------
// fp32 -> bf16 elementwise convert (8/thread)
// ---------------------------------------------------------------------------
__global__ __launch_bounds__(256) void cvt_f2b(const float* __restrict__ in,
                                               __bf16* __restrict__ out) {
    const size_t i = ((size_t)blockIdx.x * 256 + threadIdx.x) * 8;
    f32x4 a = *(const f32x4*)(in + i);
    f32x4 b = *(const f32x4*)(in + i + 4);
    bf16x8 o;
#pragma unroll
    for (int j = 0; j < 4; ++j) { o[j] = (__bf16)a[j]; o[4 + j] = (__bf16)b[j]; }
    *(bf16x8*)(out + i) = o;
}

// ---------------------------------------------------------------------------
// 32x32-tiled transpose with fp32->bf16 convert: out[C,R] = (bf16)in[R,C]^T
// ---------------------------------------------------------------------------
__global__ __launch_bounds__(256) void transpose_f2b(const float* __restrict__ in,
                                                     __bf16* __restrict__ out,
                                                     int R, int Ccols) {
    __shared__ __bf16 tile[32][33];
    const int bc = blockIdx.x * 32;
    const int br = blockIdx.y * 32;
    const int tx = threadIdx.x & 31;
    const int ty = threadIdx.x >> 5;   // 0..7
#pragma unroll
    for (int i = ty; i < 32; i += 8)
        tile[i][tx] = (__bf16)in[(size_t)(br + i) * Ccols + bc + tx];
    __syncthreads();
#pragma unroll
    for (int i = ty; i < 32; i += 8)
        out[(size_t)(bc + i) * R + br + tx] = tile[tx][i];
}

// ---------------------------------------------------------------------------
// KV partials: for (b,h, s-chunk): KVpart[dk,dv] = sum_s feat[s,dk]*q[s,dv],
// feat = elu(q)+1 computed on the fly while staging. Plus Ksum partials.
// ---------------------------------------------------------------------------
__global__ __launch_bounds__(256) void kv_partial(const __bf16* __restrict__ q,
                                                  float* __restrict__ KVpart,
                                                  float* __restrict__ Kspart) {
    __shared__ __bf16 fs[64 * 128];
    __shared__ __bf16 qs[64 * 128];
    const int bh = blockIdx.x;   // 0..15
    const int ch = blockIdx.y;   // 0..kNCH-1
    const int b = bh >> 3, h = bh & 7;
    const int t = threadIdx.x;
    const int dk0 = (t >> 4) * 8;
    const int dv0 = (t & 15) * 8;
    const int s0 = ch * kSCH;
    const size_t rowbase = ((size_t)b * kL) * kD + (size_t)h * kdh;

    float acc[8][8] = {};
    float ksacc[8] = {};

    for (int st = 0; st < kSCH / 64; ++st) {
        if (st) __syncthreads();
#pragma unroll
        for (int c = 0; c < 4; ++c) {
            int id = c * 256 + t;
            int r = id >> 4;
            int col = (id & 15) * 8;
            bf16x8 qv = *(const bf16x8*)(q + rowbase + (size_t)(s0 + st * 64 + r) * kD + col);
            *(bf16x8*)&qs[r * 128 + col] = qv;
            bf16x8 fv;
#pragma unroll
            for (int j = 0; j < 8; ++j) fv[j] = (__bf16)elu1f((float)qv[j]);
            *(bf16x8*)&fs[r * 128 + col] = fv;
        }
        __syncthreads();
        for (int s = 0; s < 64; ++s) {
            bf16x8 fv = *(const bf16x8*)&fs[s * 128 + dk0];
            bf16x8 qv = *(const bf16x8*)&qs[s * 128 + dv0];
            float fk[8], vv[8];
#pragma unroll
            for (int i = 0; i < 8; ++i) { fk[i] = (float)fv[i]; vv[i] = (float)qv[i]; }
#pragma unroll
            for (int i = 0; i < 8; ++i)
#pragma unroll
                for (int j = 0; j < 8; ++j)
                    acc[i][j] += fk[i] * vv[j];
#pragma unroll
            for (int i = 0; i < 8; ++i) ksacc[i] += fk[i];
        }
    }

    float* outp = KVpart + (((size_t)bh * kNCH + ch) << 14) + (size_t)dk0 * 128 + dv0;
#pragma unroll
    for (int i = 0; i < 8; ++i) {
        f32x4 w0, w1;
#pragma unroll
        for (int j = 0; j < 4; ++j) { w0[j] = acc[i][j]; w1[j] = acc[i][j + 4]; }
        *(f32x4*)(outp + i * 128) = w0;
        *(f32x4*)(outp + i * 128 + 4) = w1;
    }
    if ((t & 15) == 0) {
        float* kp = Kspart + ((size_t)bh * kNCH + ch) * 128 + dk0;
#pragma unroll
        for (int i = 0; i < 8; ++i) kp[i] = ksacc[i];
    }
}

__global__ __launch_bounds__(256) void kv_reduce(const float* __restrict__ part,
                                                 float* __restrict__ KV) {
    const size_t o = (size_t)blockIdx.x * 256 + threadIdx.x;  // 262144 total
    const size_t bh = o >> 14;
    const size_t rem = o & 16383;
    float s = 0.f;
#pragma unroll 4
    for (int ch = 0; ch < kNCH; ++ch)
        s += part[((bh * kNCH + ch) << 14) + rem];
    KV[o] = s;
}

__global__ __launch_bounds__(256) void ks_reduce(const float* __restrict__ part,
                                                 float* __restrict__ Ks) {
    const int o = blockIdx.x * 256 + threadIdx.x;  // 2048 total
    const int bh = o >> 7;
    const int dk = o & 127;
    float s = 0.f;
#pragma unroll 4
    for (int ch = 0; ch < kNCH; ++ch)
        s += part[(bh * kNCH + ch) * 128 + dk];
    Ks[o] = s;
}

// ---------------------------------------------------------------------------
// msg[l,dv] = Z(l) * sum_dk feat[l,dk] * KV[dk,dv],  Z = 1/(feat.Ksum + eps)
// feat staged into LDS with elu applied on the way in.
// ---------------------------------------------------------------------------
__global__ __launch_bounds__(256) void msg_kernel(const __bf16* __restrict__ q,
                                                  const float* __restrict__ KV,
                                                  const float* __restrict__ Ks,
                                                  __bf16* __restrict__ msg) {
    __shared__ __bf16 fls[64 * 128];
    __shared__ float KsS[128];
    const int bh = blockIdx.x, b = bh >> 3, h = bh & 7;
    const int rbase = blockIdx.y * 64;
    const int t = threadIdx.x;
    const size_t rowbase = ((size_t)b * kL) * kD + (size_t)h * kdh;

#pragma unroll
    for (int c = 0; c < 4; ++c) {
        int id = c * 256 + t;
        int r = id >> 4, col = (id & 15) * 8;
        bf16x8 qv = *(const bf16x8*)(q + rowbase + (size_t)(rbase + r) * kD + col);
        bf16x8 fv;
#pragma unroll
        for (int j = 0; j < 8; ++j) fv[j] = (__bf16)elu1f((float)qv[j]);
        *(bf16x8*)&fls[r * 128 + col] = fv;
    }
    if (t < 32) *(f32x4*)&KsS[t * 4] = *(const f32x4*)(Ks + bh * 128 + t * 4);
    __syncthreads();

    const int rg = t >> 4, c = t & 15, dv0 = c * 8;
    float Zi[4];
#pragma unroll
    for (int i = 0; i < 4; ++i) {
        int r = rg + i * 16;
        float p = 0.f;
#pragma unroll
        for (int j = 0; j < 8; ++j)
            p += (float)fls[r * 128 + c * 8 + j] * KsS[c * 8 + j];
        p += __shfl_xor(p, 1, 16);
        p += __shfl_xor(p, 2, 16);
        p += __shfl_xor(p, 4, 16);
        p += __shfl_xor(p, 8, 16);
        Zi[i] = 1.0f / (p + 1e-6f);
    }

    float acc[4][8] = {};
    const float* kvb = KV + ((size_t)bh << 14) + dv0;
#pragma unroll 2
    for (int dk = 0; dk < 128; ++dk) {
        f32x4 k0v = *(const f32x4*)(kvb + dk * 128);
        f32x4 k1v = *(const f32x4*)(kvb + dk * 128 + 4);
        float fv[4];
#pragma unroll
        for (int i = 0; i < 4; ++i) fv[i] = (float)fls[(rg + i * 16) * 128 + dk];
#pragma unroll
        for (int i = 0; i < 4; ++i)
#pragma unroll
            for (int j = 0; j < 4; ++j) {
                acc[i][j] += fv[i] * k0v[j];
                acc[i][4 + j] += fv[i] * k1v[j];
            }
    }

#pragma unroll
    for (int i = 0; i < 4; ++i) {
        bf16x8 o;
#pragma unroll
        for (int j = 0; j < 8; ++j) o[j] = (__bf16)(acc[i][j] * Zi[i]);
        *(bf16x8*)(msg + rowbase + (size_t)(rbase + rg + i * 16) * kD + dv0) = o;
    }
}

// ---------------------------------------------------------------------------
// out = base + layernorm(y)*g + b  (fp32 base/g/b/out, bf16 y)
// one block per 1024-wide row
// ---------------------------------------------------------------------------
__global__ __launch_bounds__(256) void ln_res(const float* __restrict__ base,
                                              const __bf16* __restrict__ y,
                                              const float* __restrict__ g,
                                              const float* __restrict__ bvec,
                                              float* __restrict__ out) {
    __shared__ float red[8];
    const int row = blockIdx.x;
    const int t = threadIdx.x;
    const size_t ro = (size_t)row * kD;
    bf16x4 yv = *(const bf16x4*)(y + ro + t * 4);
    float v[4];
    float s = 0.f, sq = 0.f;
#pragma unroll
    for (int j = 0; j < 4; ++j) { v[j] = (float)yv[j]; s += v[j]; sq += v[j] * v[j]; }
#pragma unroll
    for (int m = 1; m < 64; m <<= 1) { s += __shfl_xor(s, m); sq += __shfl_xor(sq, m); }
    const int wave = t >> 6, lane = t & 63;
    if (lane == 0) { red[wave * 2] = s; red[wave * 2 + 1] = sq; }
    __syncthreads();
    s = red[0] + red[2] + red[4] + red[6];
    sq = red[1] + red[3] + red[5] + red[7];
    const float mu = s * (1.0f / 1024.0f);
    float var = sq * (1.0f / 1024.0f) - mu * mu;
    if (var < 0.f) var = 0.f;
    const float rstd = rsqrtf(var + 1e-5f);
    f32x4 bb = *(const f32x4*)(base + ro + t * 4);
    f32x4 gg = *(const f32x4*)(g + t * 4);
    f32x4 be = *(const f32x4*)(bvec + t * 4);
    f32x4 o;
#pragma unroll
    for (int j = 0; j < 4; ++j)
        o[j] = bb[j] + (v[j] - mu) * rstd * gg[j] + be[j];
    *(f32x4*)(out + ro + t * 4) = o;
}

// ---------------------------------------------------------------------------
extern "C" void kernel_launch(void* const* d_in, const int* in_sizes, int n_in,
                              void* d_out, int out_size, void* d_ws, size_t ws_size,
                              hipStream_t stream) {
    const float* x  = (const float*)d_in[0];
    const float* Wq = (const float*)d_in[1];
    const float* Wm = (const float*)d_in[2];
    const float* W1 = (const float*)d_in[3];
    const float* W2 = (const float*)d_in[4];
    const float* g1 = (const float*)d_in[5];
    const float* b1 = (const float*)d_in[6];
    const float* g2 = (const float*)d_in[7];
    const float* b2 = (const float*)d_in[8];
    float* out = (float*)d_out;

    const size_t BLD = (size_t)kM * kD;  // 16,777,216
    // workspace layout: bf16 region then fp32 region (~182 MB total)
    __bf16* q    = (__bf16*)d_ws;        // BLD (reused as msg2)
    __bf16* msg  = q + BLD;              // BLD (reused as mlp)
    __bf16* hbuf = msg + BLD;            // 2*BLD (xb aliases first BLD)
    __bf16* WqT  = hbuf + 2 * BLD;       // 1M
    __bf16* WmT  = WqT + 1048576;        // 1M
    __bf16* W1T  = WmT + 1048576;        // 2M
    __bf16* W2T  = W1T + 2097152;        // 2M
    float* KVpart = (float*)(W2T + 2097152);               // kNCH*16*16384
    float* KV     = KVpart + (size_t)kNCH * 16 * 16384;    // 262144
    float* Kspart = KV + 16 * 16384;                       // 16*kNCH*128
    float* Ksum   = Kspart + (size_t)16 * kNCH * 128;      // 2048
    const size_t need = ((char*)(Ksum + 2048)) - (char*)d_ws;
    if (ws_size < need) return;  // output stays zero -> distinguishable signature

    __bf16* xb   = hbuf;  // x in bf16; dead before hbuf is written
    __bf16* msg2 = q;     // q dead after msg_kernel
    __bf16* mlp  = msg;   // msg dead after msg@Wm gemm

    const dim3 blk(256);

    // prep: convert x, transpose+convert weights
    cvt_f2b<<<dim3((unsigned)(BLD / 2048)), blk, 0, stream>>>(x, xb);
    transpose_f2b<<<dim3(32, 32), blk, 0, stream>>>(Wq, WqT, kD, kD);
    transpose_f2b<<<dim3(32, 32), blk, 0, stream>>>(Wm, WmT, kD, kD);
    transpose_f2b<<<dim3(64, 32), blk, 0, stream>>>(W1, W1T, kD, 2048);
    transpose_f2b<<<dim3(32, 64), blk, 0, stream>>>(W2, W2T, 2048, kD);

    // q = x @ Wq
    gemm_bt<0><<<dim3(kM / 128, kD / 128), blk, 0, stream>>>(xb, WqT, q, kM, kD, kD);
    // KV & Ksum (V=q/L and msg*L cancel)
    kv_partial<<<dim3(16, kNCH), blk, 0, stream>>>(q, KVpart, Kspart);
    kv_reduce<<<dim3(16 * 16384 / 256), blk, 0, stream>>>(KVpart, KV);
    ks_reduce<<<dim3(16 * 128 / 256), blk, 0, stream>>>(Kspart, Ksum);
    // msg = Z * (feat @ KV)
    msg_kernel<<<dim3(16, kL / 64), blk, 0, stream>>>(q, KV, Ksum, msg);
    // msg2 = msg @ Wm
    gemm_bt<0><<<dim3(kM / 128, kD / 128), blk, 0, stream>>>(msg, WmT, msg2, kM, kD, kD);
    // x1 = x + LN(msg2) -> d_out (fp32)
    ln_res<<<dim3(kM), blk, 0, stream>>>(x, msg2, g1, b1, out);
    // h = relu(msg2 @ W1)
    gemm_bt<1><<<dim3(kM / 128, 2048 / 128), blk, 0, stream>>>(msg2, W1T, hbuf, kM, 2048, kD);
    // mlp = h @ W2
    gemm_bt<0><<<dim3(kM / 128, kD / 128), blk, 0, stream>>>(hbuf, W2T, mlp, kM, kD, 2048);
    // out = x1 + LN(mlp)
    ln_res<<<dim3(kM), blk, 0, stream>>>(out, mlp, g2, b2, out);
    (void)in_sizes; (void)n_in; (void)out_size;
}

// Round 7
// 633.933 us; speedup vs baseline: 1.5896x; 1.5896x over previous
//
#include <hip/hip_runtime.h>
#include <hip/hip_bf16.h>
#include <stdint.h>

#define AS1 __attribute__((address_space(1)))
#define AS3 __attribute__((address_space(3)))

typedef __bf16 bf16x8 __attribute__((ext_vector_type(8)));
typedef __bf16 bf16x4 __attribute__((ext_vector_type(4)));
typedef float  f32x4  __attribute__((ext_vector_type(4)));

static constexpr int kL   = 8192;
static constexpr int kD   = 1024;
static constexpr int kdh  = 128;
static constexpr int kM   = 2 * kL;         // 16384 token rows
static constexpr int kNCH = 32;             // KV partial chunks over L
static constexpr int kSCH = kL / kNCH;      // 256 s-rows per chunk

__device__ __forceinline__ void async_cp16(__bf16* lds, const __bf16* g) {
    __builtin_amdgcn_global_load_lds((AS1 uint32_t*)g, (AS3 uint32_t*)lds, 16, 0, 0);
}

__device__ __forceinline__ float elu1f(float x) {
    return x > 0.0f ? x + 1.0f : __expf(x);
}

// ---------------------------------------------------------------------------
// GEMM (R5 verified best: 129us W2, 533 TF): C = A @ Bt^T, 128x128 tile,
// BK=32, 4 waves x (4x4) mfma_16x16x32_bf16. R4 swizzle staging (0 bank
// conflicts, coalesced) + single-barrier DMA double-buffer (stage k+1 during
// compute k; barrier drain has a full compute phase in flight).
// R6's direct-reg A regressed (A fetched 2x, VGPR 136, occ halved) - reverted.
// ---------------------------------------------------------------------------
template <int EPI>
__global__ __launch_bounds__(256) void gemm_bt(const __bf16* __restrict__ A,
                                               const __bf16* __restrict__ Bt,
                                               __bf16* __restrict__ C,
                                               int M, int N, int K) {
    __shared__ __bf16 As[2][128 * 32];
    __shared__ __bf16 Bs[2][128 * 32];
    const int tid  = threadIdx.x;
    const int wave = tid >> 6;
    const int lane = tid & 63;
    const int quad = lane >> 4;
    const int l16  = lane & 15;
    const int row0 = blockIdx.x * 128;
    const int col0 = blockIdx.y * 128;
    const int wm   = wave & 1;
    const int wn   = wave >> 1;

    f32x4 acc[4][4] = {};

    const int srow = lane >> 2;                          // 0..15
    const int sk8  = ((lane & 3) - (srow >> 1)) & 3;     // swizzled chunk
    const int scol = sk8 * 8;
    const __bf16* Ag0 = A  + (size_t)(row0 + wave * 32 + srow) * K + scol;
    const __bf16* Bg0 = Bt + (size_t)(col0 + wave * 32 + srow) * K + scol;
    const size_t r16 = (size_t)16 * K;
    const int ldsw = (wave * 32) * 32;

    const int fp = ((quad + (l16 >> 1)) & 3) * 8;
    const int frow = l16 * 32 + fp;

    const int nk = K >> 5;
    {
        async_cp16(&As[0][ldsw], Ag0);
        async_cp16(&As[0][ldsw + 512], Ag0 + r16);
        async_cp16(&Bs[0][ldsw], Bg0);
        async_cp16(&Bs[0][ldsw + 512], Bg0 + r16);
    }
    for (int k = 0; k < nk; ++k) {
        __syncthreads();
        if (k + 1 < nk) {
            const int nb = (k + 1) & 1;
            const int ko = (k + 1) << 5;
            async_cp16(&As[nb][ldsw], Ag0 + ko);
            async_cp16(&As[nb][ldsw + 512], Ag0 + r16 + ko);
            async_cp16(&Bs[nb][ldsw], Bg0 + ko);
            async_cp16(&Bs[nb][ldsw + 512], Bg0 + r16 + ko);
        }
        const __bf16* Asb = As[k & 1];
        const __bf16* Bsb = Bs[k & 1];
        bf16x8 af[4], bfr[4];
#pragma unroll
        for (int i = 0; i < 4; ++i)
            af[i] = *(const bf16x8*)&Asb[(wm * 4 + i) * 512 + frow];
#pragma unroll
        for (int j = 0; j < 4; ++j)
            bfr[j] = *(const bf16x8*)&Bsb[(wn * 4 + j) * 512 + frow];
#pragma unroll
        for (int i = 0; i < 4; ++i)
#pragma unroll
            for (int j = 0; j < 4; ++j)
                acc[i][j] = __builtin_amdgcn_mfma_f32_16x16x32_bf16(af[i], bfr[j], acc[i][j], 0, 0, 0);
    }

    // D layout (m89-verified): col = l16, row = quad*4 + reg
#pragma unroll
    for (int i = 0; i < 4; ++i) {
        const int row_b = row0 + wm * 64 + i * 16 + quad * 4;
#pragma unroll
        for (int j = 0; j < 4; ++j) {
            const int col = col0 + wn * 64 + j * 16 + l16;
#pragma unroll
            for (int r = 0; r < 4; ++r) {
                float v = acc[i][j][r];
                if (EPI == 1) v = v > 0.0f ? v : 0.0f;
                C[(size_t)(row_b + r) * N + col] = (__bf16)v;
            }
        }
    }
}

// ---------------------------------------------------------------------------
__global__ __launch_bounds__(256) void cvt_f2b(const float* __restrict__ in,
                                               __bf16* __restrict__ out) {
    const size_t i = ((size_t)blockIdx.x * 256 + threadIdx.x) * 8;
    f32x4 a = *(const f32x4*)(in + i);
    f32x4 b = *(const f32x4*)(in + i + 4);
    bf16x8 o;
#pragma unroll
    for (int j = 0; j < 4; ++j) { o[j] = (__bf16)a[j]; o[4 + j] = (__bf16)b[j]; }
    *(bf16x8*)(out + i) = o;
}

// ---------------------------------------------------------------------------
__global__ __launch_bounds__(256) void transpose_f2b(const float* __restrict__ in,
                                                     __bf16* __restrict__ out,
                                                     int R, int Ccols) {
    __shared__ __bf16 tile[32][33];
    const int bc = blockIdx.x * 32;
    const int br = blockIdx.y * 32;
    const int tx = threadIdx.x & 31;
    const int ty = threadIdx.x >> 5;
#pragma unroll
    for (int i = ty; i < 32; i += 8)
        tile[i][tx] = (__bf16)in[(size_t)(br + i) * Ccols + bc + tx];
    __syncthreads();
#pragma unroll
    for (int i = ty; i < 32; i += 8)
        out[(size_t)(bc + i) * R + br + tx] = tile[tx][i];
}

// ---------------------------------------------------------------------------
// KV partials: KVpart[bh,ch][dk,dv] = sum_s feat[s,dk]*q[s,dv]; Ksum partials.
// ---------------------------------------------------------------------------
__global__ __launch_bounds__(256) void kv_partial(const __bf16* __restrict__ q,
                                                  float* __restrict__ KVpart,
                                                  float* __restrict__ Kspart) {
    __shared__ __bf16 fs[64 * 128];
    __shared__ __bf16 qs[64 * 128];
    const int bh = blockIdx.x;
    const int ch = blockIdx.y;
    const int b = bh >> 3, h = bh & 7;
    const int t = threadIdx.x;
    const int dk0 = (t >> 4) * 8;
    const int dv0 = (t & 15) * 8;
    const int s0 = ch * kSCH;
    const size_t rowbase = ((size_t)b * kL) * kD + (size_t)h * kdh;

    float acc[8][8] = {};
    float ksacc[8] = {};

    for (int st = 0; st < kSCH / 64; ++st) {
        if (st) __syncthreads();
#pragma unroll
        for (int c = 0; c < 4; ++c) {
            int id = c * 256 + t;
            int r = id >> 4;
            int col = (id & 15) * 8;
            bf16x8 qv = *(const bf16x8*)(q + rowbase + (size_t)(s0 + st * 64 + r) * kD + col);
            *(bf16x8*)&qs[r * 128 + col] = qv;
            bf16x8 fv;
#pragma unroll
            for (int j = 0; j < 8; ++j) fv[j] = (__bf16)elu1f((float)qv[j]);
            *(bf16x8*)&fs[r * 128 + col] = fv;
        }
        __syncthreads();
        for (int s = 0; s < 64; ++s) {
            bf16x8 fv = *(const bf16x8*)&fs[s * 128 + dk0];
            bf16x8 qv = *(const bf16x8*)&qs[s * 128 + dv0];
            float fk[8], vv[8];
#pragma unroll
            for (int i = 0; i < 8; ++i) { fk[i] = (float)fv[i]; vv[i] = (float)qv[i]; }
#pragma unroll
            for (int i = 0; i < 8; ++i)
#pragma unroll
                for (int j = 0; j < 8; ++j)
                    acc[i][j] += fk[i] * vv[j];
#pragma unroll
            for (int i = 0; i < 8; ++i) ksacc[i] += fk[i];
        }
    }

    float* outp = KVpart + (((size_t)bh * kNCH + ch) << 14) + (size_t)dk0 * 128 + dv0;
#pragma unroll
    for (int i = 0; i < 8; ++i) {
        f32x4 w0, w1;
#pragma unroll
        for (int j = 0; j < 4; ++j) { w0[j] = acc[i][j]; w1[j] = acc[i][j + 4]; }
        *(f32x4*)(outp + i * 128) = w0;
        *(f32x4*)(outp + i * 128 + 4) = w1;
    }
    if ((t & 15) == 0) {
        float* kp = Kspart + ((size_t)bh * kNCH + ch) * 128 + dk0;
#pragma unroll
        for (int i = 0; i < 8; ++i) kp[i] = ksacc[i];
    }
}

// ---------------------------------------------------------------------------
// merged reduce: blocks [0,1024) reduce KVpart -> bf16 KVb; blocks [1024,1032)
// reduce Kspart -> fp32 Ksum. One dispatch instead of two.
// ---------------------------------------------------------------------------
__global__ __launch_bounds__(256) void reduce_kv(const float* __restrict__ KVpart,
                                                 const float* __restrict__ Kspart,
                                                 __bf16* __restrict__ KVb,
                                                 float* __restrict__ Ksum) {
    const int t = threadIdx.x;
    if (blockIdx.x < 1024) {
        const size_t o = (size_t)blockIdx.x * 256 + t;    // 262144 total
        const size_t bh = o >> 14;
        const size_t rem = o & 16383;
        float s = 0.f;
#pragma unroll 4
        for (int ch = 0; ch < kNCH; ++ch)
            s += KVpart[((bh * kNCH + ch) << 14) + rem];
        KVb[o] = (__bf16)s;
    } else {
        const int o = (blockIdx.x - 1024) * 256 + t;      // 2048 total
        const int bh = o >> 7;
        const int dk = o & 127;
        float s = 0.f;
#pragma unroll 4
        for (int ch = 0; ch < kNCH; ++ch)
            s += Kspart[(bh * kNCH + ch) * 128 + dk];
        Ksum[o] = s;
    }
}

// ---------------------------------------------------------------------------
// msg[l,dv] = Z(l) * sum_dk feat[l,dk] * KVb[dk,dv],  Z = 1/(feat.Ksum + eps)
// KVb slice (32 KB bf16) staged into LDS once per block (was: per-thread
// global loads). fls staged with elu on the way in.
// ---------------------------------------------------------------------------
__global__ __launch_bounds__(256) void msg_kernel(const __bf16* __restrict__ q,
                                                  const __bf16* __restrict__ KVb,
                                                  const float* __restrict__ Ks,
                                                  __bf16* __restrict__ msg) {
    __shared__ __bf16 fls[64 * 128];
    __shared__ __bf16 kvs[128 * 128];
    __shared__ float KsS[128];
    const int bh = blockIdx.x, b = bh >> 3, h = bh & 7;
    const int rbase = blockIdx.y * 64;
    const int t = threadIdx.x;
    const size_t rowbase = ((size_t)b * kL) * kD + (size_t)h * kdh;

#pragma unroll
    for (int c = 0; c < 4; ++c) {
        int id = c * 256 + t;
        int r = id >> 4, col = (id & 15) * 8;
        bf16x8 qv = *(const bf16x8*)(q + rowbase + (size_t)(rbase + r) * kD + col);
        bf16x8 fv;
#pragma unroll
        for (int j = 0; j < 8; ++j) fv[j] = (__bf16)elu1f((float)qv[j]);
        *(bf16x8*)&fls[r * 128 + col] = fv;
    }
    {
        const __bf16* kvg = KVb + ((size_t)bh << 14);
#pragma unroll
        for (int c = 0; c < 8; ++c) {
            int id = c * 256 + t;
            *(bf16x8*)&kvs[id * 8] = *(const bf16x8*)(kvg + id * 8);
        }
    }
    if (t < 32) *(f32x4*)&KsS[t * 4] = *(const f32x4*)(Ks + bh * 128 + t * 4);
    __syncthreads();

    const int rg = t >> 4, c = t & 15, dv0 = c * 8;
    float Zi[4];
#pragma unroll
    for (int i = 0; i < 4; ++i) {
        int r = rg + i * 16;
        float p = 0.f;
#pragma unroll
        for (int j = 0; j < 8; ++j)
            p += (float)fls[r * 128 + c * 8 + j] * KsS[c * 8 + j];
        p += __shfl_xor(p, 1, 16);
        p += __shfl_xor(p, 2, 16);
        p += __shfl_xor(p, 4, 16);
        p += __shfl_xor(p, 8, 16);
        Zi[i] = 1.0f / (p + 1e-6f);
    }

    float acc[4][8] = {};
#pragma unroll 2
    for (int dk = 0; dk < 128; ++dk) {
        bf16x8 kvv = *(const bf16x8*)&kvs[dk * 128 + dv0];
        float kf[8];
#pragma unroll
        for (int j = 0; j < 8; ++j) kf[j] = (float)kvv[j];
        float fv[4];
#pragma unroll
        for (int i = 0; i < 4; ++i) fv[i] = (float)fls[(rg + i * 16) * 128 + dk];
#pragma unroll
        for (int i = 0; i < 4; ++i)
#pragma unroll
            for (int j = 0; j < 8; ++j)
                acc[i][j] += fv[i] * kf[j];
    }

#pragma unroll
    for (int i = 0; i < 4; ++i) {
        bf16x8 o;
#pragma unroll
        for (int j = 0; j < 8; ++j) o[j] = (__bf16)(acc[i][j] * Zi[i]);
        *(bf16x8*)(msg + rowbase + (size_t)(rbase + rg + i * 16) * kD + dv0) = o;
    }
}

// ---------------------------------------------------------------------------
// out = base + layernorm(y)*g + b. One WAVE per 1024-row: no LDS, no barrier,
// 64-lane shuffle reduction; 4 rows per block. BF16BASE selects base dtype.
// ---------------------------------------------------------------------------
template <int BF16BASE>
__global__ __launch_bounds__(256) void ln_res(const void* __restrict__ basep,
                                              const __bf16* __restrict__ y,
                                              const float* __restrict__ g,
                                              const float* __restrict__ bvec,
                                              float* __restrict__ out) {
    const int wave = threadIdx.x >> 6, lane = threadIdx.x & 63;
    const int row = blockIdx.x * 4 + wave;
    const size_t ro = (size_t)row * kD + lane * 16;
    bf16x8 y0 = *(const bf16x8*)(y + ro);
    bf16x8 y1 = *(const bf16x8*)(y + ro + 8);
    float v[16];
    float s = 0.f, sq = 0.f;
#pragma unroll
    for (int j = 0; j < 8; ++j) { v[j] = (float)y0[j]; v[8 + j] = (float)y1[j]; }
#pragma unroll
    for (int j = 0; j < 16; ++j) { s += v[j]; sq += v[j] * v[j]; }
#pragma unroll
    for (int m = 1; m < 64; m <<= 1) { s += __shfl_xor(s, m); sq += __shfl_xor(sq, m); }
    const float mu = s * (1.0f / 1024.0f);
    float var = sq * (1.0f / 1024.0f) - mu * mu;
    if (var < 0.f) var = 0.f;
    const float rstd = rsqrtf(var + 1e-5f);
    const int go = lane * 16;
    float bs[16];
    if (BF16BASE) {
        bf16x8 b0 = *(const bf16x8*)((const __bf16*)basep + ro);
        bf16x8 b1 = *(const bf16x8*)((const __bf16*)basep + ro + 8);
#pragma unroll
        for (int j = 0; j < 8; ++j) { bs[j] = (float)b0[j]; bs[8 + j] = (float)b1[j]; }
    } else {
#pragma unroll
        for (int j = 0; j < 4; ++j) {
            f32x4 bb = *(const f32x4*)((const float*)basep + ro + j * 4);
#pragma unroll
            for (int r = 0; r < 4; ++r) bs[j * 4 + r] = bb[r];
        }
    }
#pragma unroll
    for (int j = 0; j < 4; ++j) {
        f32x4 gg = *(const f32x4*)(g + go + j * 4);
        f32x4 be = *(const f32x4*)(bvec + go + j * 4);
        f32x4 o;
#pragma unroll
        for (int r = 0; r < 4; ++r)
            o[r] = bs[j * 4 + r] + (v[j * 4 + r] - mu) * rstd * gg[r] + be[r];
        *(f32x4*)(out + ro + j * 4) = o;
    }
}

// ---------------------------------------------------------------------------
extern "C" void kernel_launch(void* const* d_in, const int* in_sizes, int n_in,
                              void* d_out, int out_size, void* d_ws, size_t ws_size,
                              hipStream_t stream) {
    const float* x  = (const float*)d_in[0];
    const float* Wq = (const float*)d_in[1];
    const float* Wm = (const float*)d_in[2];
    const float* W1 = (const float*)d_in[3];
    const float* W2 = (const float*)d_in[4];
    const float* g1 = (const float*)d_in[5];
    const float* b1 = (const float*)d_in[6];
    const float* g2 = (const float*)d_in[7];
    const float* b2 = (const float*)d_in[8];
    float* out = (float*)d_out;

    const size_t BLD = (size_t)kM * kD;  // 16,777,216
    __bf16* q    = (__bf16*)d_ws;        // BLD (reused as msg2)
    __bf16* msg  = q + BLD;              // BLD (reused as mlp)
    __bf16* hbuf = msg + BLD;            // 2*BLD (xb aliases first BLD)
    __bf16* WqT  = hbuf + 2 * BLD;       // 1M
    __bf16* WmT  = WqT + 1048576;        // 1M
    __bf16* W1T  = WmT + 1048576;        // 2M
    __bf16* W2T  = W1T + 2097152;        // 2M
    __bf16* KVb  = W2T + 2097152;        // 262144 bf16
    float* KVpart = (float*)(KVb + 262144);                // kNCH*16*16384 f32
    float* Kspart = KVpart + (size_t)kNCH * 16 * 16384;    // 16*kNCH*128
    float* Ksum   = Kspart + (size_t)16 * kNCH * 128;      // 2048
    const size_t need = ((char*)(Ksum + 2048)) - (char*)d_ws;
    if (ws_size < need) return;

    __bf16* xb   = hbuf;  // x in bf16; consumed by ln1 before hbuf written
    __bf16* msg2 = q;     // q dead after msg_kernel
    __bf16* mlp  = msg;   // msg dead after msg@Wm gemm

    const dim3 blk(256);

    cvt_f2b<<<dim3((unsigned)(BLD / 2048)), blk, 0, stream>>>(x, xb);
    transpose_f2b<<<dim3(32, 32), blk, 0, stream>>>(Wq, WqT, kD, kD);
    transpose_f2b<<<dim3(32, 32), blk, 0, stream>>>(Wm, WmT, kD, kD);
    transpose_f2b<<<dim3(64, 32), blk, 0, stream>>>(W1, W1T, kD, 2048);
    transpose_f2b<<<dim3(32, 64), blk, 0, stream>>>(W2, W2T, 2048, kD);

    // q = x @ Wq
    gemm_bt<0><<<dim3(kM / 128, kD / 128), blk, 0, stream>>>(xb, WqT, q, kM, kD, kD);
    // KV & Ksum (V=q/L and msg*L cancel)
    kv_partial<<<dim3(16, kNCH), blk, 0, stream>>>(q, KVpart, Kspart);
    reduce_kv<<<dim3(1032), blk, 0, stream>>>(KVpart, Kspart, KVb, Ksum);
    // msg = Z * (feat @ KV)
    msg_kernel<<<dim3(16, kL / 64), blk, 0, stream>>>(q, KVb, Ksum, msg);
    // msg2 = msg @ Wm
    gemm_bt<0><<<dim3(kM / 128, kD / 128), blk, 0, stream>>>(msg, WmT, msg2, kM, kD, kD);
    // x1 = x + LN(msg2) -> d_out   (base read as bf16 xb; hbuf not yet reused)
    ln_res<1><<<dim3(kM / 4), blk, 0, stream>>>(xb, msg2, g1, b1, out);
    // h = relu(msg2 @ W1)
    gemm_bt<1><<<dim3(kM / 128, 2048 / 128), blk, 0, stream>>>(msg2, W1T, hbuf, kM, 2048, kD);
    // mlp = h @ W2
    gemm_bt<0><<<dim3(kM / 128, kD / 128), blk, 0, stream>>>(hbuf, W2T, mlp, kM, kD, 2048);
    // out = x1 + LN(mlp)
    ln_res<0><<<dim3(kM / 4), blk, 0, stream>>>(out, mlp, g2, b2, out);
    (void)in_sizes; (void)n_in; (void)out_size;
}